// Round 1
// baseline (986.111 us; speedup 1.0000x reference)
//
#include <hip/hip_runtime.h>
#include <math.h>

// SelfSimilarity: out[b,n,m] = softmax_m( -(|x_n|^2 + |x_m|^2 - 2 x_n.x_m) / T )
// Simplification: per-row constant sq_n cancels in softmax -> logit = (2*dot - sq_m)/T.
// No max-shift needed (consistent across phases; exponents bounded ~e^9, fp32-safe).

constexpr int B = 4;
constexpr int N = 4096;
constexpr int D = 64;
constexpr int TM = 16;            // rows per block
constexpr int THREADS = 256;      // one column per thread per chunk
constexpr int CHUNKS = N / THREADS; // 16
constexpr float TEMP = 13.544f;

__global__ __launch_bounds__(THREADS, 2)
void selfsim_kernel(const float* __restrict__ x, float* __restrict__ out) {
    const int batch = blockIdx.y;
    const int row0  = blockIdx.x * TM;
    const int t     = threadIdx.x;

    const float* __restrict__ xb = x + (size_t)batch * N * D;
    float* __restrict__ ob = out + (size_t)batch * N * N;

    // exponent scale: exp((2*dot - sq)/T) = exp2( (2*dot - sq) * log2(e)/T )
    const float c = 1.4426950408889634f / TEMP;

    float rowsum[TM];
    #pragma unroll
    for (int r = 0; r < TM; ++r) rowsum[r] = 0.0f;

    // ---------------- Phase 1: row sums (no stores) ----------------
    for (int ch = 0; ch < CHUNKS; ++ch) {
        const int m = ch * THREADS + t;
        const float* __restrict__ xm = xb + (size_t)m * D;

        float v[D];
        #pragma unroll
        for (int k4 = 0; k4 < D / 4; ++k4) {
            const float4 f = *reinterpret_cast<const float4*>(xm + 4 * k4);
            v[4 * k4 + 0] = f.x; v[4 * k4 + 1] = f.y;
            v[4 * k4 + 2] = f.z; v[4 * k4 + 3] = f.w;
        }
        float sq = 0.0f;
        #pragma unroll
        for (int k = 0; k < D; ++k) sq += v[k] * v[k];

        #pragma unroll
        for (int r = 0; r < TM; ++r) {
            // uniform across the wave -> scalar loads
            const float* __restrict__ xr = xb + (size_t)(row0 + r) * D;
            float d0 = 0.f, d1 = 0.f, d2 = 0.f, d3 = 0.f;
            #pragma unroll
            for (int k = 0; k < D; k += 4) {
                d0 += v[k + 0] * xr[k + 0];
                d1 += v[k + 1] * xr[k + 1];
                d2 += v[k + 2] * xr[k + 2];
                d3 += v[k + 3] * xr[k + 3];
            }
            const float dot = (d0 + d1) + (d2 + d3);
            rowsum[r] += exp2f((2.0f * dot - sq) * c);
        }
    }

    // ---------------- Cross-thread reduction of row sums ----------------
    __shared__ float red[TM][4];
    #pragma unroll
    for (int r = 0; r < TM; ++r) {
        float s = rowsum[r];
        #pragma unroll
        for (int off = 32; off > 0; off >>= 1) s += __shfl_xor(s, off, 64);
        if ((t & 63) == 0) red[r][t >> 6] = s;
    }
    __syncthreads();

    float rinv[TM];
    #pragma unroll
    for (int r = 0; r < TM; ++r) {
        rinv[r] = 1.0f / (red[r][0] + red[r][1] + red[r][2] + red[r][3]);
    }

    // ---------------- Phase 2: recompute + normalized store ----------------
    for (int ch = 0; ch < CHUNKS; ++ch) {
        const int m = ch * THREADS + t;
        const float* __restrict__ xm = xb + (size_t)m * D;

        float v[D];
        #pragma unroll
        for (int k4 = 0; k4 < D / 4; ++k4) {
            const float4 f = *reinterpret_cast<const float4*>(xm + 4 * k4);
            v[4 * k4 + 0] = f.x; v[4 * k4 + 1] = f.y;
            v[4 * k4 + 2] = f.z; v[4 * k4 + 3] = f.w;
        }
        float sq = 0.0f;
        #pragma unroll
        for (int k = 0; k < D; ++k) sq += v[k] * v[k];

        #pragma unroll
        for (int r = 0; r < TM; ++r) {
            const float* __restrict__ xr = xb + (size_t)(row0 + r) * D;
            float d0 = 0.f, d1 = 0.f, d2 = 0.f, d3 = 0.f;
            #pragma unroll
            for (int k = 0; k < D; k += 4) {
                d0 += v[k + 0] * xr[k + 0];
                d1 += v[k + 1] * xr[k + 1];
                d2 += v[k + 2] * xr[k + 2];
                d3 += v[k + 3] * xr[k + 3];
            }
            const float dot = (d0 + d1) + (d2 + d3);
            const float e = exp2f((2.0f * dot - sq) * c);
            ob[(size_t)(row0 + r) * N + m] = e * rinv[r];
        }
    }
}

extern "C" void kernel_launch(void* const* d_in, const int* in_sizes, int n_in,
                              void* d_out, int out_size, void* d_ws, size_t ws_size,
                              hipStream_t stream) {
    const float* x = (const float*)d_in[0];
    float* out = (float*)d_out;
    dim3 grid(N / TM, B);   // 256 x 4 = 1024 blocks
    dim3 block(THREADS);
    hipLaunchKernelGGL(selfsim_kernel, grid, block, 0, stream, x, out);
}

// Round 2
// 177.834 us; speedup vs baseline: 5.5451x; 5.5451x over previous
//
#include <hip/hip_runtime.h>
#include <math.h>

// SelfSimilarity via MFMA:
// out[b,n,m] = softmax_m( -(|x_n|^2+|x_m|^2-2 x_n.x_m)/T )
//            = e_m / sum_m e_m,  e_m = exp( (2*dot(x_n,x_m) - |x_m|^2) / T )
// (per-row |x_n|^2 cancels; no max-shift needed: exponents bounded ~e^8, fp32-safe,
//  and phase1/phase2 compute identical values so normalization is exact.)
// dot via bf16 hi/lo split: x = hi + lo; dot ~= hi.hi + hi.lo + lo.hi (3 MFMAs, ~2^-17 rel err).
// -0.5*|x_m|^2 folded into the MFMA accumulator init (C/D: col=lane&15, row=(lane>>4)*4+reg).

constexpr int NB = 4;
constexpr int N = 4096;
constexpr int D = 64;
constexpr int TM = 32;            // rows per block
constexpr int THREADS = 256;      // 4 waves
constexpr int NW = 4;
constexpr int CHUNK = NW * 32;    // 128 cols per block-chunk
constexpr int CHUNKS = N / CHUNK; // 32
constexpr float TEMP = 13.544f;

typedef __attribute__((ext_vector_type(8))) short bf16x8;
typedef __attribute__((ext_vector_type(4))) float f32x4;

__device__ __forceinline__ unsigned short f2bf(float f) {
    unsigned int u = __builtin_bit_cast(unsigned int, f);
    u += 0x7FFFu + ((u >> 16) & 1u);          // RNE to bf16
    return (unsigned short)(u >> 16);
}
__device__ __forceinline__ float bf2f(unsigned short h) {
    return __builtin_bit_cast(float, (unsigned int)h << 16);
}

// load 8 consecutive fp32, split into bf16 hi/lo fragments, return sum of squares
__device__ __forceinline__ float load8(const float* __restrict__ p, bf16x8& hi, bf16x8& lo) {
    const float4 u = *reinterpret_cast<const float4*>(p);
    const float4 v = *reinterpret_cast<const float4*>(p + 4);
    float e[8] = {u.x, u.y, u.z, u.w, v.x, v.y, v.z, v.w};
    float sq = 0.f;
    #pragma unroll
    for (int j = 0; j < 8; ++j) {
        sq += e[j] * e[j];
        const unsigned short h = f2bf(e[j]);
        const float hf = bf2f(h);
        const unsigned short l = f2bf(e[j] - hf);
        hi[j] = (short)h;
        lo[j] = (short)l;
    }
    return sq;
}

// One full sweep over all columns for this block's 32 rows.
// STORE=false: accumulate row sums. STORE=true: recompute, normalize, write.
template<bool STORE>
__device__ __forceinline__ void sweep(
    const float* __restrict__ xb, float* __restrict__ ob,
    const bf16x8 (&a_hi)[2][2], const bf16x8 (&a_lo)[2][2],
    int row0, int w, int lr, int kg, float kexp,
    float (&rs)[2][4], const float (&rinv)[2][4])
{
    for (int ch = 0; ch < CHUNKS; ++ch) {
        const int cw = ch * CHUNK + w * 32;
        #pragma unroll
        for (int ct = 0; ct < 2; ++ct) {
            const int colbase = cw + 16 * ct;

            // B fragments: col = lane&15 (row m of x), k = kg*8 + j (+32*kt)
            bf16x8 b_hi[2], b_lo[2];
            float sq = 0.f;
            const float* bp = xb + (size_t)(colbase + lr) * D + kg * 8;
            #pragma unroll
            for (int kt = 0; kt < 2; ++kt)
                sq += load8(bp + kt * 32, b_hi[kt], b_lo[kt]);
            // lanes sharing a column (same lane&15) hold disjoint k-groups -> reduce
            sq += __shfl_xor(sq, 16, 64);
            sq += __shfl_xor(sq, 32, 64);

            f32x4 acc[2];
            #pragma unroll
            for (int i = 0; i < 2; ++i) {
                const float ci = -0.5f * sq;   // fold -|x_m|^2/2 into C init
                acc[i] = f32x4{ci, ci, ci, ci};
                #pragma unroll
                for (int kt = 0; kt < 2; ++kt) {
                    acc[i] = __builtin_amdgcn_mfma_f32_16x16x32_bf16(a_hi[i][kt], b_hi[kt], acc[i], 0, 0, 0);
                    acc[i] = __builtin_amdgcn_mfma_f32_16x16x32_bf16(a_hi[i][kt], b_lo[kt], acc[i], 0, 0, 0);
                    acc[i] = __builtin_amdgcn_mfma_f32_16x16x32_bf16(a_lo[i][kt], b_hi[kt], acc[i], 0, 0, 0);
                }
            }

            #pragma unroll
            for (int i = 0; i < 2; ++i) {
                #pragma unroll
                for (int q = 0; q < 4; ++q) {
                    const float e = __builtin_amdgcn_exp2f(acc[i][q] * kexp);
                    if (STORE) {
                        const size_t off =
                            (size_t)(row0 + 16 * i + kg * 4 + q) * N + (colbase + lr);
                        ob[off] = e * rinv[i][q];
                    } else {
                        rs[i][q] += e;
                    }
                }
            }
        }
    }
}

__global__ void selfsim_mfma(const float* __restrict__ x, float* __restrict__ out) {
    const int batch = blockIdx.y;
    const int row0  = blockIdx.x * TM;
    const int t     = threadIdx.x;
    const int w     = t >> 6;
    const int lane  = t & 63;
    const int lr    = lane & 15;
    const int kg    = lane >> 4;

    const float* __restrict__ xb = x + (size_t)batch * N * D;
    float* __restrict__ ob = out + (size_t)batch * N * N;

    // exp((2*acc)/T) = exp2(acc * 2*log2(e)/T)
    const float kexp = 2.0f * 1.4426950408889634f / TEMP;

    // Persistent A fragments: rows row0 + 16*i + lr, k = 32*kt + kg*8 + j
    bf16x8 a_hi[2][2], a_lo[2][2];
    #pragma unroll
    for (int i = 0; i < 2; ++i) {
        const float* rp = xb + (size_t)(row0 + 16 * i + lr) * D + kg * 8;
        #pragma unroll
        for (int kt = 0; kt < 2; ++kt)
            (void)load8(rp + kt * 32, a_hi[i][kt], a_lo[i][kt]);
    }

    float rs[2][4];
    #pragma unroll
    for (int i = 0; i < 2; ++i)
        #pragma unroll
        for (int q = 0; q < 4; ++q) rs[i][q] = 0.f;

    float rinv[2][4];   // dummy for phase 1

    // -------- Phase 1: row sums (no stores) --------
    sweep<false>(xb, ob, a_hi, a_lo, row0, w, lr, kg, kexp, rs, rinv);

    // -------- Reduce row sums across lanes and waves --------
    __shared__ float lds[NW][TM];
    __shared__ float ldsr[TM];
    #pragma unroll
    for (int i = 0; i < 2; ++i) {
        #pragma unroll
        for (int q = 0; q < 4; ++q) {
            float s = rs[i][q];
            s += __shfl_xor(s, 1, 64);
            s += __shfl_xor(s, 2, 64);
            s += __shfl_xor(s, 4, 64);
            s += __shfl_xor(s, 8, 64);
            if (lr == 0) lds[w][16 * i + kg * 4 + q] = s;
        }
    }
    __syncthreads();
    if (t < TM) {
        const float s = lds[0][t] + lds[1][t] + lds[2][t] + lds[3][t];
        ldsr[t] = 1.0f / s;
    }
    __syncthreads();
    #pragma unroll
    for (int i = 0; i < 2; ++i)
        #pragma unroll
        for (int q = 0; q < 4; ++q)
            rinv[i][q] = ldsr[16 * i + kg * 4 + q];

    // -------- Phase 2: recompute + normalized store --------
    sweep<true>(xb, ob, a_hi, a_lo, row0, w, lr, kg, kexp, rs, rinv);
}

extern "C" void kernel_launch(void* const* d_in, const int* in_sizes, int n_in,
                              void* d_out, int out_size, void* d_ws, size_t ws_size,
                              hipStream_t stream) {
    const float* x = (const float*)d_in[0];
    float* out = (float*)d_out;
    dim3 grid(N / TM, NB);   // 128 x 4 = 512 blocks
    dim3 block(THREADS);
    hipLaunchKernelGGL(selfsim_mfma, grid, block, 0, stream, x, out);
}

// Round 3
// 172.840 us; speedup vs baseline: 5.7053x; 1.0289x over previous
//
#include <hip/hip_runtime.h>
#include <math.h>

// SelfSimilarity:
// out[b,n,m] = softmax_m( -(|x_n|^2+|x_m|^2-2 x_n.x_m)/T )
//            = e_m / sum_m e_m,   e_m = exp2( kexp*dot(x_n,x_m) - 0.5*kexp*|x_m|^2 )
// with kexp = 2*log2(e)/T. Per-row |x_n|^2 cancels; no max-shift needed (bounded exps,
// identical values in both phases -> exact normalization).
//
// Pre-pass converts x to bf16 hi/lo (unscaled: row side; kexp-scaled: col side) and
// csq[m] = -0.5*kexp*|x_m|^2 into d_ws, so the hot kernels do no conversions.
// dot via bf16 split: x = h+l; x.y ~= h.h' + h.l' + l.h'  (3 MFMAs, ~2^-17 rel).
//
// MFMA role swap (A=cols, B=rows): D row (kg*4+q) = output COLUMN, D col (lane&15) =
// output ROW -> each lane's f32x4 acc = 4 consecutive output columns of one row
// -> float4 coalesced stores, scalar per-lane row sums.

constexpr int NB = 4;
constexpr int N = 4096;
constexpr int D = 64;
constexpr float TEMP = 13.544f;
constexpr int CSPL = 4;             // column splits (partial softmax sums)
constexpr int COLS = N / CSPL;      // 1024 cols per block
constexpr int TMB = 32;             // rows per block
constexpr int NW = 4;               // waves per block
constexpr int THREADS = 256;
constexpr int TILES = COLS / (NW * 16);  // 16 col-tiles per wave

typedef __attribute__((ext_vector_type(8))) short bf16x8;
typedef __attribute__((ext_vector_type(4))) float f32x4;

__device__ __forceinline__ unsigned short f2bf(float f) {
    unsigned int u = __builtin_bit_cast(unsigned int, f);
    u += 0x7FFFu + ((u >> 16) & 1u);   // RNE
    return (unsigned short)(u >> 16);
}
__device__ __forceinline__ float bf2f(unsigned short h) {
    return __builtin_bit_cast(float, (unsigned int)h << 16);
}

// ---------------- Pre-pass: convert + squares ----------------
// wave: 8 rows, lane l -> row wbase + (l>>3), elements (l&7)*8 .. +8
__global__ __launch_bounds__(THREADS)
void prep_kernel(const float* __restrict__ x,
                 short* __restrict__ xhi, short* __restrict__ xlo,
                 short* __restrict__ xhs, short* __restrict__ xls,
                 float* __restrict__ csq) {
    const int t = threadIdx.x;
    const int lane = t & 63, w = t >> 6;
    const int row = blockIdx.x * 32 + w * 8 + (lane >> 3);
    const int seg = lane & 7;
    const float S = 2.0f * 1.4426950408889634f / TEMP;   // kexp

    const float* p = x + (size_t)row * D + seg * 8;
    const float4 u = *reinterpret_cast<const float4*>(p);
    const float4 v = *reinterpret_cast<const float4*>(p + 4);
    float e[8] = {u.x, u.y, u.z, u.w, v.x, v.y, v.z, v.w};

    float sq = 0.f;
    #pragma unroll
    for (int j = 0; j < 8; ++j) sq += e[j] * e[j];
    sq += __shfl_xor(sq, 1, 64);
    sq += __shfl_xor(sq, 2, 64);
    sq += __shfl_xor(sq, 4, 64);

    bf16x8 h, l, hs, ls;
    #pragma unroll
    for (int j = 0; j < 8; ++j) {
        const unsigned short hb = f2bf(e[j]);
        h[j] = (short)hb;
        l[j] = (short)f2bf(e[j] - bf2f(hb));
        const float es = e[j] * S;
        const unsigned short hsb = f2bf(es);
        hs[j] = (short)hsb;
        ls[j] = (short)f2bf(es - bf2f(hsb));
    }
    const int off = row * D + seg * 8;
    *reinterpret_cast<bf16x8*>(xhi + off) = h;
    *reinterpret_cast<bf16x8*>(xlo + off) = l;
    *reinterpret_cast<bf16x8*>(xhs + off) = hs;
    *reinterpret_cast<bf16x8*>(xls + off) = ls;
    if (seg == 0) csq[row] = -0.5f * S * sq;
}

// ---------------- Main sweep (templated): rowsum / normalize+store ----------------
template<bool STORE>
__global__ __launch_bounds__(THREADS)
void sweep_kernel(const short* __restrict__ xhi, const short* __restrict__ xlo,
                  const short* __restrict__ xhs, const short* __restrict__ xls,
                  const float* __restrict__ csq, float* __restrict__ parts,
                  float* __restrict__ out) {
    const int b = blockIdx.y;
    const int s = blockIdx.z;
    const int row0 = blockIdx.x * TMB;
    const int t = threadIdx.x;
    const int w = t >> 6, lane = t & 63;
    const int lr = lane & 15, kg = lane >> 4;
    const int rbase = b * N;

    // persistent row-side fragments (MFMA B operand), rows row0 + 16*i + lr
    bf16x8 bh[2][2], bl[2][2];
    #pragma unroll
    for (int i = 0; i < 2; ++i) {
        const int r = rbase + row0 + 16 * i + lr;
        const short* ph = xhi + r * D + kg * 8;
        const short* pl = xlo + r * D + kg * 8;
        #pragma unroll
        for (int kt = 0; kt < 2; ++kt) {
            bh[i][kt] = *reinterpret_cast<const bf16x8*>(ph + kt * 32);
            bl[i][kt] = *reinterpret_cast<const bf16x8*>(pl + kt * 32);
        }
    }

    __shared__ float rlds[TMB];
    __shared__ float red[NW][TMB];
    float rinv0 = 0.f, rinv1 = 0.f;
    if (STORE) {
        if (t < TMB) {
            const f32x4 pp = *reinterpret_cast<const f32x4*>(
                parts + (size_t)(rbase + row0 + t) * CSPL);
            rlds[t] = 1.0f / ((pp[0] + pp[1]) + (pp[2] + pp[3]));
        }
        __syncthreads();
        rinv0 = rlds[lr];
        rinv1 = rlds[16 + lr];
    }

    float rs0 = 0.f, rs1 = 0.f;
    const int cb0 = s * COLS + w * 16;

    #pragma unroll 2
    for (int j = 0; j < TILES; ++j) {
        const int col = cb0 + j * (NW * 16);
        const int c = rbase + col;

        const short* pa_h = xhs + (size_t)(c + lr) * D + kg * 8;
        const short* pa_l = xls + (size_t)(c + lr) * D + kg * 8;
        const bf16x8 ah0 = *reinterpret_cast<const bf16x8*>(pa_h);
        const bf16x8 ah1 = *reinterpret_cast<const bf16x8*>(pa_h + 32);
        const bf16x8 al0 = *reinterpret_cast<const bf16x8*>(pa_l);
        const bf16x8 al1 = *reinterpret_cast<const bf16x8*>(pa_l + 32);
        const f32x4 c4 = *reinterpret_cast<const f32x4*>(csq + c + kg * 4);

        f32x4 acc0 = c4, acc1 = c4;
        acc0 = __builtin_amdgcn_mfma_f32_16x16x32_bf16(ah0, bh[0][0], acc0, 0, 0, 0);
        acc0 = __builtin_amdgcn_mfma_f32_16x16x32_bf16(ah1, bh[0][1], acc0, 0, 0, 0);
        acc0 = __builtin_amdgcn_mfma_f32_16x16x32_bf16(ah0, bl[0][0], acc0, 0, 0, 0);
        acc0 = __builtin_amdgcn_mfma_f32_16x16x32_bf16(ah1, bl[0][1], acc0, 0, 0, 0);
        acc0 = __builtin_amdgcn_mfma_f32_16x16x32_bf16(al0, bh[0][0], acc0, 0, 0, 0);
        acc0 = __builtin_amdgcn_mfma_f32_16x16x32_bf16(al1, bh[0][1], acc0, 0, 0, 0);

        acc1 = __builtin_amdgcn_mfma_f32_16x16x32_bf16(ah0, bh[1][0], acc1, 0, 0, 0);
        acc1 = __builtin_amdgcn_mfma_f32_16x16x32_bf16(ah1, bh[1][1], acc1, 0, 0, 0);
        acc1 = __builtin_amdgcn_mfma_f32_16x16x32_bf16(ah0, bl[1][0], acc1, 0, 0, 0);
        acc1 = __builtin_amdgcn_mfma_f32_16x16x32_bf16(ah1, bl[1][1], acc1, 0, 0, 0);
        acc1 = __builtin_amdgcn_mfma_f32_16x16x32_bf16(al0, bh[1][0], acc1, 0, 0, 0);
        acc1 = __builtin_amdgcn_mfma_f32_16x16x32_bf16(al1, bh[1][1], acc1, 0, 0, 0);

        f32x4 e0, e1;
        #pragma unroll
        for (int q = 0; q < 4; ++q) {
            e0[q] = __builtin_amdgcn_exp2f(acc0[q]);
            e1[q] = __builtin_amdgcn_exp2f(acc1[q]);
        }

        if (STORE) {
            f32x4 o0, o1;
            #pragma unroll
            for (int q = 0; q < 4; ++q) { o0[q] = e0[q] * rinv0; o1[q] = e1[q] * rinv1; }
            float* p0 = out + (size_t)(rbase + row0 + lr) * N + col + kg * 4;
            float* p1 = out + (size_t)(rbase + row0 + 16 + lr) * N + col + kg * 4;
            *reinterpret_cast<f32x4*>(p0) = o0;
            *reinterpret_cast<f32x4*>(p1) = o1;
        } else {
            rs0 += (e0[0] + e0[1]) + (e0[2] + e0[3]);
            rs1 += (e1[0] + e1[1]) + (e1[2] + e1[3]);
        }
    }

    if (!STORE) {
        rs0 += __shfl_xor(rs0, 16, 64); rs0 += __shfl_xor(rs0, 32, 64);
        rs1 += __shfl_xor(rs1, 16, 64); rs1 += __shfl_xor(rs1, 32, 64);
        if (lane < 16) { red[w][lr] = rs0; red[w][16 + lr] = rs1; }
        __syncthreads();
        if (t < TMB) {
            const float sum = (red[0][t] + red[1][t]) + (red[2][t] + red[3][t]);
            parts[(size_t)(rbase + row0 + t) * CSPL + s] = sum;
        }
    }
}

extern "C" void kernel_launch(void* const* d_in, const int* in_sizes, int n_in,
                              void* d_out, int out_size, void* d_ws, size_t ws_size,
                              hipStream_t stream) {
    const float* x = (const float*)d_in[0];
    float* out = (float*)d_out;

    constexpr int NE = NB * N * D;       // 1048576 elements
    short* xhi = (short*)d_ws;
    short* xlo = xhi + NE;
    short* xhs = xlo + NE;
    short* xls = xhs + NE;
    float* csq = (float*)(xls + NE);     // NB*N floats
    float* parts = csq + NB * N;         // NB*N*CSPL floats

    // pre-pass: 16384 rows, 32 rows/block
    hipLaunchKernelGGL(prep_kernel, dim3(NB * N / 32), dim3(THREADS), 0, stream,
                       x, xhi, xlo, xhs, xls, csq);

    dim3 grid(N / TMB, NB, CSPL);        // 128 x 4 x 4 = 2048 blocks
    hipLaunchKernelGGL((sweep_kernel<false>), grid, dim3(THREADS), 0, stream,
                       xhi, xlo, xhs, xls, csq, parts, out);
    hipLaunchKernelGGL((sweep_kernel<true>), grid, dim3(THREADS), 0, stream,
                       xhi, xlo, xhs, xls, csq, parts, out);
}

// Round 5
// 136.577 us; speedup vs baseline: 7.2202x; 1.2655x over previous
//
#include <hip/hip_runtime.h>
#include <math.h>

// SelfSimilarity:
// out[b,n,m] = softmax_m( -(|x_n|^2+|x_m|^2-2 x_n.x_m)/T )
//            = e_m / sum_m e_m,   e_m = exp2( kexp*dot(x_n,x_m) - 0.5*kexp*|x_m|^2 )
// kexp = 2*log2(e)/T; per-row |x_n|^2 cancels; no max-shift needed (bounded exps,
// identical recompute in both phases -> exact normalization).
// prep: bf16 hi/lo rows (xhi/xlo) + kexp-scaled hi/lo cols (xhs/xls) + csq.
// phase1 (rowsum): 2-product ah.(bh+bl)  (~0.5% rowsum err, fine for normalization).
// phase2 (store):  3-product ah.bh+ah.bl+al.bh (~2^-17 rel), LDS-staged epilogue ->
//                  fully linear 1KB/wave nontemporal stores (fix 16-row x 64B scatter).

constexpr int NB = 4;
constexpr int N = 4096;
constexpr int D = 64;
constexpr float TEMP = 13.544f;
constexpr int CSPL = 4;
constexpr int COLS = N / CSPL;           // 1024 cols per block
constexpr int TMB = 32;                  // rows per block
constexpr int NW = 4;
constexpr int THREADS = 256;
constexpr int TILES = COLS / (NW * 16);  // 16 col-tiles (of 64 cols) per block

typedef __attribute__((ext_vector_type(8))) short bf16x8;
typedef __attribute__((ext_vector_type(4))) float f32x4;

__device__ __forceinline__ unsigned short f2bf(float f) {
    unsigned int u = __builtin_bit_cast(unsigned int, f);
    u += 0x7FFFu + ((u >> 16) & 1u);   // RNE
    return (unsigned short)(u >> 16);
}
__device__ __forceinline__ float bf2f(unsigned short h) {
    return __builtin_bit_cast(float, (unsigned int)h << 16);
}

// LDS float-index of the 4-float group written by (wave w, kgroup kg, lanerow lr, acc)
// fragment-order layout + XOR(w<<2) swizzle: write side per-lane contiguous,
// read side bank-distribution equivalent to linear.
__device__ __forceinline__ int lidx(int w, int kg, int lr, int acc) {
    return ((((w << 6) + (kg << 4) + lr) << 3) + (acc << 2)) ^ (w << 2);
}

// ---------------- Pre-pass: convert + squares ----------------
__global__ __launch_bounds__(THREADS)
void prep_kernel(const float* __restrict__ x,
                 short* __restrict__ xhi, short* __restrict__ xlo,
                 short* __restrict__ xhs, short* __restrict__ xls,
                 float* __restrict__ csq) {
    const int t = threadIdx.x;
    const int lane = t & 63, w = t >> 6;
    const int row = blockIdx.x * 32 + w * 8 + (lane >> 3);
    const int seg = lane & 7;
    const float S = 2.0f * 1.4426950408889634f / TEMP;   // kexp

    const float* p = x + (size_t)row * D + seg * 8;
    const float4 u = *reinterpret_cast<const float4*>(p);
    const float4 v = *reinterpret_cast<const float4*>(p + 4);
    float e[8] = {u.x, u.y, u.z, u.w, v.x, v.y, v.z, v.w};

    float sq = 0.f;
    #pragma unroll
    for (int j = 0; j < 8; ++j) sq += e[j] * e[j];
    sq += __shfl_xor(sq, 1, 64);
    sq += __shfl_xor(sq, 2, 64);
    sq += __shfl_xor(sq, 4, 64);

    bf16x8 h, l, hs, ls;
    #pragma unroll
    for (int j = 0; j < 8; ++j) {
        const unsigned short hb = f2bf(e[j]);
        h[j] = (short)hb;
        l[j] = (short)f2bf(e[j] - bf2f(hb));
        const float es = e[j] * S;
        const unsigned short hsb = f2bf(es);
        hs[j] = (short)hsb;
        ls[j] = (short)f2bf(es - bf2f(hsb));
    }
    const int off = row * D + seg * 8;
    *reinterpret_cast<bf16x8*>(xhi + off) = h;
    *reinterpret_cast<bf16x8*>(xlo + off) = l;
    *reinterpret_cast<bf16x8*>(xhs + off) = hs;
    *reinterpret_cast<bf16x8*>(xls + off) = ls;
    if (seg == 0) csq[row] = -0.5f * S * sq;
}

// ---------------- Main sweep: rowsum / normalize+store ----------------
template<bool STORE>
__global__ __launch_bounds__(THREADS)
void sweep_kernel(const short* __restrict__ xhi, const short* __restrict__ xlo,
                  const short* __restrict__ xhs, const short* __restrict__ xls,
                  const float* __restrict__ csq, float* __restrict__ parts,
                  float* __restrict__ out) {
    const int b = blockIdx.y;
    const int s = blockIdx.z;
    const int row0 = blockIdx.x * TMB;
    const int t = threadIdx.x;
    const int w = t >> 6, lane = t & 63;
    const int lr = lane & 15, kg = lane >> 4;
    const int rbase = b * N;

    // persistent row-side fragments (MFMA B operand), rows row0 + 16*i + lr
    bf16x8 bh[2][2], bl[2][2];
    #pragma unroll
    for (int i = 0; i < 2; ++i) {
        const int r = rbase + row0 + 16 * i + lr;
        const short* ph = xhi + r * D + kg * 8;
        const short* pl = xlo + r * D + kg * 8;
        #pragma unroll
        for (int kt = 0; kt < 2; ++kt) {
            bh[i][kt] = *reinterpret_cast<const bf16x8*>(ph + kt * 32);
            bl[i][kt] = *reinterpret_cast<const bf16x8*>(pl + kt * 32);
        }
    }

    __shared__ float red[NW][TMB];
    __shared__ float rlds[TMB];
    __shared__ float buf[2][2048];   // phase-2 staging (16 KB, double-buffered)

    if (STORE) {
        if (t < TMB) {
            const f32x4 pp = *reinterpret_cast<const f32x4*>(
                parts + (size_t)(rbase + row0 + t) * CSPL);
            rlds[t] = 1.0f / ((pp[0] + pp[1]) + (pp[2] + pp[3]));
        }
        __syncthreads();
    }

    float rs0 = 0.f, rs1 = 0.f;
    const int cb0 = s * COLS + w * 16;

    for (int j = 0; j < TILES; ++j) {
        const int col = cb0 + j * (NW * 16);
        const int c = rbase + col;

        const short* pa_h = xhs + (size_t)(c + lr) * D + kg * 8;
        const bf16x8 ah0 = *reinterpret_cast<const bf16x8*>(pa_h);
        const bf16x8 ah1 = *reinterpret_cast<const bf16x8*>(pa_h + 32);
        const f32x4 c4 = *reinterpret_cast<const f32x4*>(csq + c + kg * 4);

        f32x4 acc0 = c4, acc1 = c4;
        // 2 products: ah.(bh+bl) — both phases
        acc0 = __builtin_amdgcn_mfma_f32_16x16x32_bf16(ah0, bh[0][0], acc0, 0, 0, 0);
        acc0 = __builtin_amdgcn_mfma_f32_16x16x32_bf16(ah1, bh[0][1], acc0, 0, 0, 0);
        acc0 = __builtin_amdgcn_mfma_f32_16x16x32_bf16(ah0, bl[0][0], acc0, 0, 0, 0);
        acc0 = __builtin_amdgcn_mfma_f32_16x16x32_bf16(ah1, bl[0][1], acc0, 0, 0, 0);
        acc1 = __builtin_amdgcn_mfma_f32_16x16x32_bf16(ah0, bh[1][0], acc1, 0, 0, 0);
        acc1 = __builtin_amdgcn_mfma_f32_16x16x32_bf16(ah1, bh[1][1], acc1, 0, 0, 0);
        acc1 = __builtin_amdgcn_mfma_f32_16x16x32_bf16(ah0, bl[1][0], acc1, 0, 0, 0);
        acc1 = __builtin_amdgcn_mfma_f32_16x16x32_bf16(ah1, bl[1][1], acc1, 0, 0, 0);

        if (STORE) {
            // third product al.bh for full precision
            const short* pa_l = xls + (size_t)(c + lr) * D + kg * 8;
            const bf16x8 al0 = *reinterpret_cast<const bf16x8*>(pa_l);
            const bf16x8 al1 = *reinterpret_cast<const bf16x8*>(pa_l + 32);
            acc0 = __builtin_amdgcn_mfma_f32_16x16x32_bf16(al0, bh[0][0], acc0, 0, 0, 0);
            acc0 = __builtin_amdgcn_mfma_f32_16x16x32_bf16(al1, bh[0][1], acc0, 0, 0, 0);
            acc1 = __builtin_amdgcn_mfma_f32_16x16x32_bf16(al0, bh[1][0], acc1, 0, 0, 0);
            acc1 = __builtin_amdgcn_mfma_f32_16x16x32_bf16(al1, bh[1][1], acc1, 0, 0, 0);

            f32x4 o0, o1;
            #pragma unroll
            for (int q = 0; q < 4; ++q) {
                o0[q] = __builtin_amdgcn_exp2f(acc0[q]);
                o1[q] = __builtin_amdgcn_exp2f(acc1[q]);
            }
            // stage fragments to LDS (per-lane contiguous 32B)
            float* bj = buf[j & 1];
            *reinterpret_cast<f32x4*>(bj + lidx(w, kg, lr, 0)) = o0;
            *reinterpret_cast<f32x4*>(bj + lidx(w, kg, lr, 1)) = o1;
            __syncthreads();
            // linear nontemporal stores: 2 rounds x (wave = 4 rows x 64 cols = 1KB)
            const int scol = s * COLS + j * (NW * 16);
            #pragma unroll
            for (int p = 0; p < 2; ++p) {
                const int f = p * 1024 + t * 4;
                const int row = f >> 6;
                const int cl = f & 63;
                f32x4 v = *reinterpret_cast<const f32x4*>(
                    bj + lidx(cl >> 4, (cl >> 2) & 3, row & 15, row >> 4));
                v *= rlds[row];
                __builtin_nontemporal_store(v, reinterpret_cast<f32x4*>(
                    out + (size_t)(rbase + row0 + row) * N + scol + cl));
            }
        } else {
            #pragma unroll
            for (int q = 0; q < 4; ++q) {
                rs0 += __builtin_amdgcn_exp2f(acc0[q]);
                rs1 += __builtin_amdgcn_exp2f(acc1[q]);
            }
        }
    }

    if (!STORE) {
        // lanes sharing an output row differ in kg (lane>>4)
        rs0 += __shfl_xor(rs0, 16, 64); rs0 += __shfl_xor(rs0, 32, 64);
        rs1 += __shfl_xor(rs1, 16, 64); rs1 += __shfl_xor(rs1, 32, 64);
        if (lane < 16) { red[w][lr] = rs0; red[w][16 + lr] = rs1; }
        __syncthreads();
        if (t < TMB) {
            const float sum = (red[0][t] + red[1][t]) + (red[2][t] + red[3][t]);
            parts[(size_t)(rbase + row0 + t) * CSPL + s] = sum;
        }
    }
}

extern "C" void kernel_launch(void* const* d_in, const int* in_sizes, int n_in,
                              void* d_out, int out_size, void* d_ws, size_t ws_size,
                              hipStream_t stream) {
    const float* x = (const float*)d_in[0];
    float* out = (float*)d_out;

    constexpr int NE = NB * N * D;       // 1048576 elements
    short* xhi = (short*)d_ws;
    short* xlo = xhi + NE;
    short* xhs = xlo + NE;
    short* xls = xhs + NE;
    float* csq = (float*)(xls + NE);     // NB*N floats
    float* parts = csq + NB * N;         // NB*N*CSPL floats

    hipLaunchKernelGGL(prep_kernel, dim3(NB * N / 32), dim3(THREADS), 0, stream,
                       x, xhi, xlo, xhs, xls, csq);

    dim3 grid(N / TMB, NB, CSPL);        // 128 x 4 x 4 = 2048 blocks
    hipLaunchKernelGGL((sweep_kernel<false>), grid, dim3(THREADS), 0, stream,
                       xhi, xlo, xhs, xls, csq, parts, out);
    hipLaunchKernelGGL((sweep_kernel<true>), grid, dim3(THREADS), 0, stream,
                       xhi, xlo, xhs, xls, csq, parts, out);
}

// Round 7
// 131.957 us; speedup vs baseline: 7.4730x; 1.0350x over previous
//
#include <hip/hip_runtime.h>
#include <math.h>

// SelfSimilarity:
// out[b,n,m] = softmax_m( -(|x_n|^2+|x_m|^2-2 x_n.x_m)/T )
//            = e_m / sum_m e_m,   e_m = exp2( kexp*dot(x_n,x_m) - 0.5*kexp*|x_m|^2 )
// kexp = 2*log2(e)/T; per-row |x_n|^2 cancels; no max-shift needed (bounded exps).
// prep: bf16 hi/lo rows (xhi/xlo) + kexp-scaled hi/lo cols (xhs/xls) + csq.
// phase1 (rowsum): SINGLE product ah.bh (4 MFMA/tile). The dominant rowsum error is
//   the DIAGONAL term (|x|^2-magnitude exponent); corrected exactly at normalization:
//   sum' = sum - e1_diag + exp2(-csq[R])
//   where e1_diag replays phase-1's bf16 diag arithmetic, and exp2(-csq) is the TRUE
//   diagonal of the rescaled numerator (NOT 1 -- that was R6's bug: the canceled row
//   constant exp(-sq_n/T) rescales the diagonal to exp(+sq_n/T) = exp2(-csq)).
// phase2 (store): 3-product ah.bh+ah.bl+al.bh (~2^-17 rel), rinv folded pre-LDS,
//   LDS-staged epilogue -> linear nontemporal float4 stores.

constexpr int NB = 4;
constexpr int N = 4096;
constexpr int D = 64;
constexpr float TEMP = 13.544f;
constexpr int CSPL = 4;
constexpr int COLS = N / CSPL;           // 1024 cols per block
constexpr int TMB = 32;                  // rows per block
constexpr int NW = 4;
constexpr int THREADS = 256;
constexpr int TILES = COLS / (NW * 16);  // 16 col-tiles (of 64 cols) per block

typedef __attribute__((ext_vector_type(8))) short bf16x8;
typedef __attribute__((ext_vector_type(4))) float f32x4;

__device__ __forceinline__ unsigned short f2bf(float f) {
    unsigned int u = __builtin_bit_cast(unsigned int, f);
    u += 0x7FFFu + ((u >> 16) & 1u);   // RNE
    return (unsigned short)(u >> 16);
}
__device__ __forceinline__ float bf2f(unsigned short h) {
    return __builtin_bit_cast(float, (unsigned int)h << 16);
}

// LDS float-index of the 4-float group written by (wave w, kgroup kg, lanerow lr, acc)
__device__ __forceinline__ int lidx(int w, int kg, int lr, int acc) {
    return ((((w << 6) + (kg << 4) + lr) << 3) + (acc << 2)) ^ (w << 2);
}

// ---------------- Pre-pass: convert + squares ----------------
__global__ __launch_bounds__(THREADS)
void prep_kernel(const float* __restrict__ x,
                 short* __restrict__ xhi, short* __restrict__ xlo,
                 short* __restrict__ xhs, short* __restrict__ xls,
                 float* __restrict__ csq) {
    const int t = threadIdx.x;
    const int lane = t & 63, w = t >> 6;
    const int row = blockIdx.x * 32 + w * 8 + (lane >> 3);
    const int seg = lane & 7;
    const float S = 2.0f * 1.4426950408889634f / TEMP;   // kexp

    const float* p = x + (size_t)row * D + seg * 8;
    const float4 u = *reinterpret_cast<const float4*>(p);
    const float4 v = *reinterpret_cast<const float4*>(p + 4);
    float e[8] = {u.x, u.y, u.z, u.w, v.x, v.y, v.z, v.w};

    float sq = 0.f;
    #pragma unroll
    for (int j = 0; j < 8; ++j) sq += e[j] * e[j];
    sq += __shfl_xor(sq, 1, 64);
    sq += __shfl_xor(sq, 2, 64);
    sq += __shfl_xor(sq, 4, 64);

    bf16x8 h, l, hs, ls;
    #pragma unroll
    for (int j = 0; j < 8; ++j) {
        const unsigned short hb = f2bf(e[j]);
        h[j] = (short)hb;
        l[j] = (short)f2bf(e[j] - bf2f(hb));
        const float es = e[j] * S;
        const unsigned short hsb = f2bf(es);
        hs[j] = (short)hsb;
        ls[j] = (short)f2bf(es - bf2f(hsb));
    }
    const int off = row * D + seg * 8;
    *reinterpret_cast<bf16x8*>(xhi + off) = h;
    *reinterpret_cast<bf16x8*>(xlo + off) = l;
    *reinterpret_cast<bf16x8*>(xhs + off) = hs;
    *reinterpret_cast<bf16x8*>(xls + off) = ls;
    if (seg == 0) csq[row] = -0.5f * S * sq;
}

// ---------------- Main sweep: rowsum / normalize+store ----------------
template<bool STORE>
__global__ __launch_bounds__(THREADS)
void sweep_kernel(const short* __restrict__ xhi, const short* __restrict__ xlo,
                  const short* __restrict__ xhs, const short* __restrict__ xls,
                  const float* __restrict__ csq, float* __restrict__ parts,
                  float* __restrict__ out) {
    const int b = blockIdx.y;
    const int s = blockIdx.z;
    const int row0 = blockIdx.x * TMB;
    const int t = threadIdx.x;
    const int w = t >> 6, lane = t & 63;
    const int lr = lane & 15, kg = lane >> 4;
    const int rbase = b * N;

    // persistent row-side fragments (MFMA B operand), rows row0 + 16*i + lr
    bf16x8 bh[2][2], bl[2][2];
    #pragma unroll
    for (int i = 0; i < 2; ++i) {
        const int r = rbase + row0 + 16 * i + lr;
        const short* ph = xhi + r * D + kg * 8;
        #pragma unroll
        for (int kt = 0; kt < 2; ++kt)
            bh[i][kt] = *reinterpret_cast<const bf16x8*>(ph + kt * 32);
        if (STORE) {
            const short* pl = xlo + r * D + kg * 8;
            #pragma unroll
            for (int kt = 0; kt < 2; ++kt)
                bl[i][kt] = *reinterpret_cast<const bf16x8*>(pl + kt * 32);
        }
    }

    __shared__ float red[NW][TMB];
    __shared__ float rlds[TMB];
    __shared__ float buf[2][2048];   // phase-2 staging (16 KB, double-buffered)

    float rinv0 = 0.f, rinv1 = 0.f;
    if (STORE) {
        if (t < TMB) {
            const int R = rbase + row0 + t;
            const f32x4 pp = *reinterpret_cast<const f32x4*>(parts + (size_t)R * CSPL);
            const float sum = (pp[0] + pp[1]) + (pp[2] + pp[3]);
            // replay phase1's single-product diag term in matching bf16 arithmetic
            float s1 = 0.f;
            #pragma unroll
            for (int kc = 0; kc < D / 8; ++kc) {
                const bf16x8 hsv = *reinterpret_cast<const bf16x8*>(xhs + (size_t)R * D + kc * 8);
                const bf16x8 hv  = *reinterpret_cast<const bf16x8*>(xhi + (size_t)R * D + kc * 8);
                #pragma unroll
                for (int j = 0; j < 8; ++j)
                    s1 += bf2f((unsigned short)hsv[j]) * bf2f((unsigned short)hv[j]);
            }
            const float cR = csq[R];
            const float e1d = __builtin_amdgcn_exp2f(s1 + cR);
            const float etd = __builtin_amdgcn_exp2f(-cR);   // true rescaled diagonal
            rlds[t] = 1.0f / (sum - e1d + etd);
        }
        __syncthreads();
        rinv0 = rlds[lr];
        rinv1 = rlds[16 + lr];
    }

    float rs0 = 0.f, rs1 = 0.f;
    const int cb0 = s * COLS + w * 16;

    #pragma unroll 2
    for (int j = 0; j < TILES; ++j) {
        const int col = cb0 + j * (NW * 16);
        const int c = rbase + col;

        const short* pa_h = xhs + (size_t)(c + lr) * D + kg * 8;
        const bf16x8 ah0 = *reinterpret_cast<const bf16x8*>(pa_h);
        const bf16x8 ah1 = *reinterpret_cast<const bf16x8*>(pa_h + 32);
        const f32x4 c4 = *reinterpret_cast<const f32x4*>(csq + c + kg * 4);

        f32x4 acc0 = c4, acc1 = c4;
        // single product ah.bh (both phases)
        acc0 = __builtin_amdgcn_mfma_f32_16x16x32_bf16(ah0, bh[0][0], acc0, 0, 0, 0);
        acc0 = __builtin_amdgcn_mfma_f32_16x16x32_bf16(ah1, bh[0][1], acc0, 0, 0, 0);
        acc1 = __builtin_amdgcn_mfma_f32_16x16x32_bf16(ah0, bh[1][0], acc1, 0, 0, 0);
        acc1 = __builtin_amdgcn_mfma_f32_16x16x32_bf16(ah1, bh[1][1], acc1, 0, 0, 0);

        if (STORE) {
            // products 2 and 3 for full precision: ah.bl + al.bh
            const short* pa_l = xls + (size_t)(c + lr) * D + kg * 8;
            const bf16x8 al0 = *reinterpret_cast<const bf16x8*>(pa_l);
            const bf16x8 al1 = *reinterpret_cast<const bf16x8*>(pa_l + 32);
            acc0 = __builtin_amdgcn_mfma_f32_16x16x32_bf16(ah0, bl[0][0], acc0, 0, 0, 0);
            acc0 = __builtin_amdgcn_mfma_f32_16x16x32_bf16(ah1, bl[0][1], acc0, 0, 0, 0);
            acc0 = __builtin_amdgcn_mfma_f32_16x16x32_bf16(al0, bh[0][0], acc0, 0, 0, 0);
            acc0 = __builtin_amdgcn_mfma_f32_16x16x32_bf16(al1, bh[0][1], acc0, 0, 0, 0);
            acc1 = __builtin_amdgcn_mfma_f32_16x16x32_bf16(ah0, bl[1][0], acc1, 0, 0, 0);
            acc1 = __builtin_amdgcn_mfma_f32_16x16x32_bf16(ah1, bl[1][1], acc1, 0, 0, 0);
            acc1 = __builtin_amdgcn_mfma_f32_16x16x32_bf16(al0, bh[1][0], acc1, 0, 0, 0);
            acc1 = __builtin_amdgcn_mfma_f32_16x16x32_bf16(al1, bh[1][1], acc1, 0, 0, 0);

            f32x4 o0, o1;
            #pragma unroll
            for (int q = 0; q < 4; ++q) {
                o0[q] = __builtin_amdgcn_exp2f(acc0[q]) * rinv0;
                o1[q] = __builtin_amdgcn_exp2f(acc1[q]) * rinv1;
            }
            float* bj = buf[j & 1];
            *reinterpret_cast<f32x4*>(bj + lidx(w, kg, lr, 0)) = o0;
            *reinterpret_cast<f32x4*>(bj + lidx(w, kg, lr, 1)) = o1;
            __syncthreads();
            // linear nontemporal stores: 2 rounds x (wave = 4 rows x 64 cols)
            const int scol = s * COLS + j * (NW * 16);
            #pragma unroll
            for (int p = 0; p < 2; ++p) {
                const int f = p * 1024 + t * 4;
                const int row = f >> 6;
                const int cl = f & 63;
                const f32x4 v = *reinterpret_cast<const f32x4*>(
                    bj + lidx(cl >> 4, (cl >> 2) & 3, row & 15, row >> 4));
                __builtin_nontemporal_store(v, reinterpret_cast<f32x4*>(
                    out + (size_t)(rbase + row0 + row) * N + scol + cl));
            }
        } else {
            #pragma unroll
            for (int q = 0; q < 4; ++q) {
                rs0 += __builtin_amdgcn_exp2f(acc0[q]);
                rs1 += __builtin_amdgcn_exp2f(acc1[q]);
            }
        }
    }

    if (!STORE) {
        // lanes sharing an output row differ in kg (lane>>4)
        rs0 += __shfl_xor(rs0, 16, 64); rs0 += __shfl_xor(rs0, 32, 64);
        rs1 += __shfl_xor(rs1, 16, 64); rs1 += __shfl_xor(rs1, 32, 64);
        if (lane < 16) { red[w][lr] = rs0; red[w][16 + lr] = rs1; }
        __syncthreads();
        if (t < TMB) {
            const float sum = (red[0][t] + red[1][t]) + (red[2][t] + red[3][t]);
            parts[(size_t)(rbase + row0 + t) * CSPL + s] = sum;
        }
    }
}

extern "C" void kernel_launch(void* const* d_in, const int* in_sizes, int n_in,
                              void* d_out, int out_size, void* d_ws, size_t ws_size,
                              hipStream_t stream) {
    const float* x = (const float*)d_in[0];
    float* out = (float*)d_out;

    constexpr int NE = NB * N * D;       // 1048576 elements
    short* xhi = (short*)d_ws;
    short* xlo = xhi + NE;
    short* xhs = xlo + NE;
    short* xls = xhs + NE;
    float* csq = (float*)(xls + NE);     // NB*N floats
    float* parts = csq + NB * N;         // NB*N*CSPL floats

    hipLaunchKernelGGL(prep_kernel, dim3(NB * N / 32), dim3(THREADS), 0, stream,
                       x, xhi, xlo, xhs, xls, csq);

    dim3 grid(N / TMB, NB, CSPL);        // 128 x 4 x 4 = 2048 blocks
    hipLaunchKernelGGL((sweep_kernel<false>), grid, dim3(THREADS), 0, stream,
                       xhi, xlo, xhs, xls, csq, parts, out);
    hipLaunchKernelGGL((sweep_kernel<true>), grid, dim3(THREADS), 0, stream,
                       xhi, xlo, xhs, xls, csq, parts, out);
}